// Round 5
// baseline (675.019 us; speedup 1.0000x reference)
//
#include <hip/hip_runtime.h>
#include <hip/hip_bf16.h>

// Problem: B=32, S=1024, D=1024, dm=1024, 16 heads x 64
#define DM 1024
#define NB 32

typedef __bf16 bf16_t;
typedef __attribute__((ext_vector_type(8))) __bf16 bf16x8;
typedef __attribute__((ext_vector_type(4))) float  f32x4;

// address-space typedefs for global_load_lds
typedef __attribute__((address_space(1))) void gas_void;
typedef __attribute__((address_space(3))) void las_void;

__device__ __forceinline__ void async_lds16(const bf16_t* g, bf16_t* l) {
    // 16B/lane direct global->LDS DMA. LDS dest must be wave-uniform base +
    // lane*16 (all call sites obey: lds byte = (i*512 + tid)*16).
    __builtin_amdgcn_global_load_lds((gas_void*)g, (las_void*)l, 16, 0, 0);
}

__device__ inline float bf2f(bf16_t v) {
    union { unsigned short s; __bf16 b; } u; u.b = v;
    union { unsigned int i; float f; } w; w.i = ((unsigned int)u.s) << 16;
    return w.f;
}
__device__ inline bf16_t f2bf(float f) {
    union { unsigned int i; float f; } w; w.f = f;
    unsigned int r = (w.i + 0x7FFFu + ((w.i >> 16) & 1u)) >> 16;
    union { unsigned short s; __bf16 b; } u; u.s = (unsigned short)r;
    return u.b;
}

enum EpiMode { EPI_NONE = 0, EPI_BIAS_ROW = 1, EPI_BIAS_COL = 2, EPI_SCALE = 3 };

// ---- dtype probe: mode=1 if x is fp32, mode=0 if bf16 ----
__global__ void detect_mode(const unsigned short* __restrict__ x, int* __restrict__ mode)
{
    if (threadIdx.x == 0 && blockIdx.x == 0) {
        int hits = 0;
        for (int i = 0; i < 2048; ++i) {
            unsigned e = (x[i] >> 7) & 0xFFu;
            hits += (e >= 0x8Du) ? 1 : 0;
        }
        *mode = (hits >= 16) ? 1 : 0;
    }
}

// ---- convert x (elements [off, off+n8*8)) to bf16 ----
__global__ void convert_x(const void* __restrict__ xin, bf16_t* __restrict__ xb,
                          const int* __restrict__ modep, long long off, long long n8)
{
    const long long i = (long long)blockIdx.x * blockDim.x + threadIdx.x;
    if (i >= n8) return;
    bf16x8 o;
    if (*modep) {
        const float* s = (const float*)xin + off + i * 8;
#pragma unroll
        for (int j = 0; j < 8; ++j) o[j] = f2bf(s[j]);
    } else {
        o = *(const bf16x8*)((const bf16_t*)xin + off + i * 8);
    }
    *(bf16x8*)(xb + i * 8) = o;
}

// ---- transpose the three weight matrices -> bf16 Wt[n][k] = W[k][n] ----
__global__ void transpose3(const void* __restrict__ Wq, const void* __restrict__ Wk,
                           const void* __restrict__ Wv, bf16_t* __restrict__ Wt,
                           const int* __restrict__ modep)
{
    const int md = *modep;
    const void* src = (blockIdx.z == 0) ? Wq : (blockIdx.z == 1) ? Wk : Wv;
    bf16_t* dst = Wt + (size_t)blockIdx.z * DM * DM;
    __shared__ bf16_t T[64][72];
    const int tid = threadIdx.x;
    const int r  = tid >> 2;   // 0..63
    const int cp = tid & 3;    // 16 elems each
    const int r0 = blockIdx.y * 64;  // k block
    const int c0 = blockIdx.x * 64;  // n block
    const size_t base = (size_t)(r0 + r) * DM + c0 + cp * 16;
    bf16_t tmp[16];
    if (md) {
        const float* s = (const float*)src + base;
#pragma unroll
        for (int j = 0; j < 16; ++j) tmp[j] = f2bf(s[j]);
    } else {
        const bf16_t* s = (const bf16_t*)src + base;
        bf16x8 a = *(const bf16x8*)s;
        bf16x8 b = *(const bf16x8*)(s + 8);
#pragma unroll
        for (int j = 0; j < 8; ++j) { tmp[j] = a[j]; tmp[8 + j] = b[j]; }
    }
#pragma unroll
    for (int j = 0; j < 16; ++j) T[cp * 16 + j][r] = tmp[j];
    __syncthreads();
    bf16_t* d = dst + (size_t)(c0 + r) * DM + r0 + cp * 16;
    bf16x8 w0, w1;
#pragma unroll
    for (int j = 0; j < 8; ++j) w0[j] = T[r][cp * 16 + j];
#pragma unroll
    for (int j = 0; j < 8; ++j) w1[j] = T[r][cp * 16 + 8 + j];
    *(bf16x8*)d = w0;
    *(bf16x8*)(d + 8) = w1;
}

// ============================================================================
// 256x256 NT gemm, 4-phase schedule with DEEP PREFETCH (T2+T3+T4+T5).
// 512 threads = 8 waves; per K-tile (BK=64) 4 phases; phase p computes
// quadrant (row-half p&1, col-half p>>1), 16 MFMA 16x16x32.
// R5: staging FRONT-LOADED (2 slots @p0, 2 slots @p1) so every counted-vmcnt
// publication waits on loads issued >= 3 PHASES earlier. R2-R4 published at
// 1-phase distance -> phase length pinned to the HBM round-trip (latency
// equilibrium, ~1700 cyc/phase, MfmaUtil stuck ~30%). 3-phase distance
// breaks it; in-flight loads never below 4 (T4: never drain).
// Slots: 0=A-h0, 1=B-h0, 2=A-h1, 3=B-h1.  Reads at top of consuming phase:
//   p0: af0<-s0, bg0<-s1; p1: af1<-s2; p2: bg1<-s3; p3: none (regs live).
// Wait/barrier ledger (steady state, verified per-slot; 2 loads per slot):
//   p0-end vmcnt(6)+bar -> publishes s2  (issued p1(t-1), 3 phases back)
//   p1-end vmcnt(8)+bar -> publishes s3  (issued p1(t-1), 3 phases back)
//   p2-end: NO wait, NO barrier (p2+p3 fuse into one 32-MFMA cluster)
//   p3-end vmcnt(4)+bar -> publishes s0',s1' (issued p0(t), 3 phases back)
// Overwrite safety: stages target buf nxt while reads target buf cur;
// cross-tile overwrite of cur is separated by the p3-end barrier.
// Swizzle (T2): LDS linear (gload_lds constraint), global SOURCE kc^=(row&7),
// fragment reads apply the same XOR -> conflict-free (measured 0).
// ============================================================================
template <int MODE, bool DUALOUT>
__global__ __launch_bounds__(512, 2)
void gemm_nt8(const bf16_t* __restrict__ A, long long sA,
              const bf16_t* __restrict__ B, long long sB,
              void* __restrict__ C, long long sC, long long cOff,
              const void* __restrict__ bias, const int* __restrict__ modep,
              float scale)
{
    constexpr int K = 1024;
    constexpr int NT = K / 64;          // 16 K-tiles
    extern __shared__ bf16_t L[];       // 2*4*8192 bf16 = 128 KiB

    // ---- XCD-aware bijective swizzle (grid is 4 x 4 x z, nwg % 8 == 0) ----
    int bx, by, z;
    {
        const int nwg  = 16 * (int)gridDim.z;
        const int orig = (int)blockIdx.x + 4 * ((int)blockIdx.y + 4 * (int)blockIdx.z);
        const int nid  = (orig & 7) * (nwg >> 3) + (orig >> 3);
        bx = nid & 3; by = (nid >> 2) & 3; z = nid >> 4;
    }

    const bf16_t* Ab = A + (size_t)z * (size_t)sA;
    const bf16_t* Bb = B + (size_t)z * (size_t)sB;
    const int gm0 = by * 256, gn0 = bx * 256;

    const int tid  = threadIdx.x;
    const int lane = tid & 63;
    const int w    = tid >> 6;      // 0..7
    const int rb   = w >> 1;        // 0..3: 32-row band within each row-half
    const int cb   = w & 1;         // 0..1: 64-col band within each col-half
    const int lm   = lane & 15;
    const int kg   = lane >> 4;     // 0..3

    f32x4 acc[4][2][4];
#pragma unroll
    for (int p = 0; p < 4; ++p)
#pragma unroll
        for (int i = 0; i < 2; ++i)
#pragma unroll
            for (int j = 0; j < 4; ++j) acc[p][i][j] = (f32x4)0.0f;

    // fragment register sets
    bf16x8 af0[2][2], af1[2][2], bg0[4][2], bg1[4][2];

    // stage slot s of K-tile kt into buffer b (2 x global_load_lds / thread)
    // slots: 0=A-h0, 1=B-h0, 2=A-h1, 3=B-h1
    auto stage = [&](int kt, int s, int b) {
        const bf16_t* P  = (s & 1) ? Bb : Ab;
        const int     g0 = (s & 1) ? gn0 : gm0;
        const int     h  = (s >= 2) ? 1 : 0;
        bf16_t* dst = L + (b * 4 + s) * 8192;
#pragma unroll
        for (int i = 0; i < 2; ++i) {
            const int ci  = i * 512 + tid;
            const int row = ci >> 3;
            const int kc  = (ci & 7) ^ (row & 7);   // pre-swizzled source
            async_lds16(P + (size_t)(g0 + h * 128 + row) * K + kt * 64 + kc * 8,
                        dst + ci * 8);
        }
    };

    // fragment read: row r (0..127) within a half-slot, 8-elem chunk kc (0..7)
    auto rdfrag = [&](int b, int s, int r, int kc) -> bf16x8 {
        const int byte = r * 128 + ((kc ^ (r & 7)) * 16);
        return *(const bf16x8*)((const char*)(L + (b * 4 + s) * 8192) + byte);
    };
    auto rdA = [&](int b, int s, bf16x8 (&dst)[2][2]) {
#pragma unroll
        for (int mt = 0; mt < 2; ++mt)
#pragma unroll
            for (int kk = 0; kk < 2; ++kk)
                dst[mt][kk] = rdfrag(b, s, rb * 32 + mt * 16 + lm, kk * 4 + kg);
    };
    auto rdB = [&](int b, int s, bf16x8 (&dst)[4][2]) {
#pragma unroll
        for (int nt = 0; nt < 4; ++nt)
#pragma unroll
            for (int kk = 0; kk < 2; ++kk)
                dst[nt][kk] = rdfrag(b, s, cb * 64 + nt * 16 + lm, kk * 4 + kg);
    };

#define MFMA_PHASE(P, AF, BG)                                                  \
    __builtin_amdgcn_s_setprio(1);                                             \
    _Pragma("unroll")                                                          \
    for (int kk = 0; kk < 2; ++kk)                                             \
        _Pragma("unroll")                                                      \
        for (int mt = 0; mt < 2; ++mt)                                         \
            _Pragma("unroll")                                                  \
            for (int nt = 0; nt < 4; ++nt)                                     \
                acc[P][mt][nt] = __builtin_amdgcn_mfma_f32_16x16x32_bf16(      \
                    AF[mt][kk], BG[nt][kk], acc[P][mt][nt], 0, 0, 0);          \
    __builtin_amdgcn_s_setprio(0);

    // ---- prologue: stage tile0's 4 slots; publish s0,s1 (vmcnt(4)) ----
#pragma unroll
    for (int s = 0; s < 4; ++s) stage(0, s, 0);
    asm volatile("s_waitcnt vmcnt(4)" ::: "memory");
    __builtin_amdgcn_s_barrier();

#pragma unroll 1
    for (int kt = 0; kt < NT; ++kt) {
        const int cur = kt & 1;
        const int nxt = cur ^ 1;
        const int nkt = (kt + 1 < NT) ? kt + 1 : 0;    // dummy re-stage on last

        // ---- p0: read af0<-s0, bg0<-s1 | stage s0',s1' | MFMA q0 ----
        rdA(cur, 0, af0);
        rdB(cur, 1, bg0);
        stage(nkt, 0, nxt);
        stage(nkt, 1, nxt);
        __builtin_amdgcn_sched_barrier(0);
        MFMA_PHASE(0, af0, bg0)
        __builtin_amdgcn_sched_barrier(0);
        asm volatile("s_waitcnt vmcnt(6)" ::: "memory");   // publish s2
        __builtin_amdgcn_s_barrier();

        // ---- p1: read af1<-s2 | stage s2',s3' | MFMA q1 ----
        rdA(cur, 2, af1);
        stage(nkt, 2, nxt);
        stage(nkt, 3, nxt);
        __builtin_amdgcn_sched_barrier(0);
        MFMA_PHASE(1, af1, bg0)
        __builtin_amdgcn_sched_barrier(0);
        asm volatile("s_waitcnt vmcnt(8)" ::: "memory");   // publish s3
        __builtin_amdgcn_s_barrier();

        // ---- p2+p3 fused: read bg1<-s3 | MFMA q2, q3 (32-MFMA cluster) ----
        rdB(cur, 3, bg1);
        __builtin_amdgcn_sched_barrier(0);
        MFMA_PHASE(2, af0, bg1)
        MFMA_PHASE(3, af1, bg1)
        __builtin_amdgcn_sched_barrier(0);
        asm volatile("s_waitcnt vmcnt(4)" ::: "memory");   // publish s0',s1'
        __builtin_amdgcn_s_barrier();
    }
#undef MFMA_PHASE

    // ---- epilogue: C/D layout col=lane&15, row=kg*4+r (m89/m91-verified) ----
    // phase p = quadrant (row-half p&1, col-half p>>1)
    const int md = *modep;
#pragma unroll
    for (int p = 0; p < 4; ++p) {
        const int rbase = gm0 + (p & 1) * 128 + rb * 32;
        const int cbase = gn0 + (p >> 1) * 128 + cb * 64;
#pragma unroll
        for (int mt = 0; mt < 2; ++mt) {
            float rbias[4];
            if (MODE == EPI_BIAS_ROW) {
#pragma unroll
                for (int r = 0; r < 4; ++r) {
                    const int i = rbase + mt * 16 + kg * 4 + r;
                    rbias[r] = md ? ((const float*)bias)[i] : bf2f(((const bf16_t*)bias)[i]);
                }
            }
#pragma unroll
            for (int nt = 0; nt < 4; ++nt) {
                const int col = cbase + nt * 16 + lm;
                float cbias = 0.f;
                if (MODE == EPI_BIAS_COL)
                    cbias = md ? ((const float*)bias)[col] : bf2f(((const bf16_t*)bias)[col]);
#pragma unroll
                for (int r = 0; r < 4; ++r) {
                    const int row = rbase + mt * 16 + kg * 4 + r;
                    float vv = acc[p][mt][nt][r];
                    if (MODE == EPI_BIAS_ROW) vv += rbias[r];
                    if (MODE == EPI_BIAS_COL) vv += cbias;
                    if (MODE == EPI_SCALE)    vv *= scale;
                    const size_t off = (size_t)cOff + (size_t)z * sC + (size_t)row * 1024 + col;
                    if (DUALOUT && md) ((float*)C)[off] = vv;
                    else               ((bf16_t*)C)[off] = f2bf(vv);
                }
            }
        }
    }
}

// In-place chunked softmax + transpose on Y[zb][DM][DM] (bf16 internal).
__global__ void softmax_t_inplace(bf16_t* __restrict__ Y)
{
    const int b = blockIdx.z;
    int idx = blockIdx.x;           // 0..135
    int I = 0;
    while (idx >= 16 - I) { idx -= 16 - I; ++I; }
    const int J = I + idx;

    const int tid = threadIdx.x;
    const int r  = tid >> 2;
    const int cp = tid & 3;

    bf16_t* base = Y + ((size_t)b << 20);
    bf16_t* t0 = base + (size_t)(I * 64 + r) * DM + J * 64 + cp * 16;
    bf16_t* t1 = base + (size_t)(J * 64 + r) * DM + I * 64 + cp * 16;

    __shared__ bf16_t P0[64][72];
    __shared__ bf16_t P1[64][72];

    bf16x8 a0 = *(const bf16x8*)t0;
    bf16x8 a1 = *(const bf16x8*)(t0 + 8);
    bf16x8 c0v, c1v;
    if (J != I) { c0v = *(const bf16x8*)t1; c1v = *(const bf16x8*)(t1 + 8); }

    {
        float f[16];
#pragma unroll
        for (int j = 0; j < 8; ++j) f[j] = bf2f(a0[j]);
#pragma unroll
        for (int j = 0; j < 8; ++j) f[8 + j] = bf2f(a1[j]);
        float m = -1e30f;
#pragma unroll
        for (int j = 0; j < 16; ++j) m = fmaxf(m, f[j]);
        m = fmaxf(m, __shfl_xor(m, 1));
        m = fmaxf(m, __shfl_xor(m, 2));
        float s = 0.f;
#pragma unroll
        for (int j = 0; j < 16; ++j) { f[j] = __expf(f[j] - m); s += f[j]; }
        s += __shfl_xor(s, 1);
        s += __shfl_xor(s, 2);
        const float inv = 1.0f / s;
#pragma unroll
        for (int j = 0; j < 16; ++j) P0[cp * 16 + j][r] = f2bf(f[j] * inv);
    }
    if (J != I) {
        float f[16];
#pragma unroll
        for (int j = 0; j < 8; ++j) f[j] = bf2f(c0v[j]);
#pragma unroll
        for (int j = 0; j < 8; ++j) f[8 + j] = bf2f(c1v[j]);
        float m = -1e30f;
#pragma unroll
        for (int j = 0; j < 16; ++j) m = fmaxf(m, f[j]);
        m = fmaxf(m, __shfl_xor(m, 1));
        m = fmaxf(m, __shfl_xor(m, 2));
        float s = 0.f;
#pragma unroll
        for (int j = 0; j < 16; ++j) { f[j] = __expf(f[j] - m); s += f[j]; }
        s += __shfl_xor(s, 1);
        s += __shfl_xor(s, 2);
        const float inv = 1.0f / s;
#pragma unroll
        for (int j = 0; j < 16; ++j) P1[cp * 16 + j][r] = f2bf(f[j] * inv);
    }
    __syncthreads();

    bf16x8 w0, w1;
#pragma unroll
    for (int j = 0; j < 8; ++j) w0[j] = P0[r][cp * 16 + j];
#pragma unroll
    for (int j = 0; j < 8; ++j) w1[j] = P0[r][cp * 16 + 8 + j];
    *(bf16x8*)t1 = w0;
    *(bf16x8*)(t1 + 8) = w1;
    if (J != I) {
#pragma unroll
        for (int j = 0; j < 8; ++j) w0[j] = P1[r][cp * 16 + j];
#pragma unroll
        for (int j = 0; j < 8; ++j) w1[j] = P1[r][cp * 16 + 8 + j];
        *(bf16x8*)t0 = w0;
        *(bf16x8*)(t0 + 8) = w1;
    }
}

extern "C" void kernel_launch(void* const* d_in, const int* in_sizes, int n_in,
                              void* d_out, int out_size, void* d_ws, size_t ws_size,
                              hipStream_t stream)
{
    const void* x  = d_in[0];
    const void* Wq = d_in[1];
    const void* bq = d_in[2];
    const void* Wk = d_in[3];
    const void* bk = d_in[4];
    const void* Wv = d_in[5];
    const void* bv = d_in[6];

    // one-time: allow 128 KiB dynamic LDS on the gemm instantiations
    static bool attr_done = false;
    if (!attr_done) {
        hipFuncSetAttribute((const void*)gemm_nt8<EPI_BIAS_ROW, false>,
                            hipFuncAttributeMaxDynamicSharedMemorySize, 131072);
        hipFuncSetAttribute((const void*)gemm_nt8<EPI_BIAS_COL, false>,
                            hipFuncAttributeMaxDynamicSharedMemorySize, 131072);
        hipFuncSetAttribute((const void*)gemm_nt8<EPI_SCALE, false>,
                            hipFuncAttributeMaxDynamicSharedMemorySize, 131072);
        hipFuncSetAttribute((const void*)gemm_nt8<EPI_NONE, true>,
                            hipFuncAttributeMaxDynamicSharedMemorySize, 131072);
        attr_done = true;
    }

    // ws layout: [mode int | pad to 256] [Wt 6MB] [xb CB] [qt CB] [kt CB] [y CB]
    char* ws = (char*)d_ws;
    int* mode = (int*)ws;
    const size_t MB2 = (size_t)DM * DM * 2;
    const size_t hdr = 256;
    int CB = NB;
    while (CB > 1 && hdr + 3 * MB2 + 4 * (size_t)CB * MB2 > ws_size) CB >>= 1;

    bf16_t* Wt = (bf16_t*)(ws + hdr);
    bf16_t* xb = (bf16_t*)(ws + hdr + 3 * MB2);
    bf16_t* qt = xb + (size_t)CB * DM * DM;
    bf16_t* kt = qt + (size_t)CB * DM * DM;
    bf16_t* y  = kt + (size_t)CB * DM * DM;
    bf16_t* v  = qt;   // qt dead after QK^T; reuse for V

    detect_mode<<<1, 64, 0, stream>>>((const unsigned short*)x, mode);
    transpose3<<<dim3(16, 16, 3), 256, 0, stream>>>(Wq, Wk, Wv, Wt, mode);

    const long long msz = (long long)DM * DM;
    for (int c = 0; c < NB; c += CB) {
        const int zb = (NB - c < CB) ? (NB - c) : CB;
        const long long n8 = (long long)zb * msz / 8;
        convert_x<<<(int)((n8 + 255) / 256), 256, 0, stream>>>(x, xb, mode, (long long)c * msz, n8);

        const dim3 g8(4, 4, zb), blk8(512);
        // qt[b][d][s] = Wq^T x^T + bq (row bias)
        gemm_nt8<EPI_BIAS_ROW, false><<<g8, blk8, 131072, stream>>>(Wt, 0, xb, msz, qt, msz, 0, bq, mode, 1.f);
        // kt[b][e][s]
        gemm_nt8<EPI_BIAS_ROW, false><<<g8, blk8, 131072, stream>>>(Wt + msz, 0, xb, msz, kt, msz, 0, bk, mode, 1.f);
        // y[b][d][e] = qt . kt / 8
        gemm_nt8<EPI_SCALE, false><<<g8, blk8, 131072, stream>>>(qt, msz, kt, msz, y, msz, 0, nullptr, mode, 0.125f);
        // y <- softmax+transpose in place
        softmax_t_inplace<<<dim3(136, 1, zb), 256, 0, stream>>>(y);
        // v[b][s][d] = x Wv^T + bv (col bias) -> qt slab
        gemm_nt8<EPI_BIAS_COL, false><<<g8, blk8, 131072, stream>>>(xb, msz, Wt + 2 * msz, 0, v, msz, 0, bv, mode, 1.f);
        // out[b][s][e] = v . y   (dual-dtype output)
        gemm_nt8<EPI_NONE, true><<<g8, blk8, 131072, stream>>>(v, msz, y, msz, d_out, msz, (long long)c * msz, nullptr, mode, 1.f);
    }
}

// Round 6
// 649.279 us; speedup vs baseline: 1.0396x; 1.0396x over previous
//
#include <hip/hip_runtime.h>
#include <hip/hip_bf16.h>

// Problem: B=32, S=1024, D=1024, dm=1024, 16 heads x 64
#define DM 1024
#define NB 32

typedef __bf16 bf16_t;
typedef __attribute__((ext_vector_type(4))) __bf16 bf16x4;
typedef __attribute__((ext_vector_type(8))) __bf16 bf16x8;
typedef __attribute__((ext_vector_type(4))) float  f32x4;

// address-space typedefs for global_load_lds
typedef __attribute__((address_space(1))) void gas_void;
typedef __attribute__((address_space(3))) void las_void;

__device__ __forceinline__ void async_lds16(const bf16_t* g, bf16_t* l) {
    // 16B/lane direct global->LDS DMA. LDS dest must be wave-uniform base +
    // lane*16 (all call sites obey: lds byte = (i*512 + tid)*16).
    __builtin_amdgcn_global_load_lds((gas_void*)g, (las_void*)l, 16, 0, 0);
}

__device__ inline float bf2f(bf16_t v) {
    union { unsigned short s; __bf16 b; } u; u.b = v;
    union { unsigned int i; float f; } w; w.i = ((unsigned int)u.s) << 16;
    return w.f;
}
__device__ inline bf16_t f2bf(float f) {
    union { unsigned int i; float f; } w; w.f = f;
    unsigned int r = (w.i + 0x7FFFu + ((w.i >> 16) & 1u)) >> 16;
    union { unsigned short s; __bf16 b; } u; u.s = (unsigned short)r;
    return u.b;
}

enum EpiMode { EPI_NONE = 0, EPI_BIAS_ROW = 1, EPI_BIAS_COL = 2, EPI_SCALE = 3,
               EPI_SMAXT = 4 };

// ---- dtype probe: mode=1 if x is fp32, mode=0 if bf16 ----
__global__ void detect_mode(const unsigned short* __restrict__ x, int* __restrict__ mode)
{
    if (threadIdx.x == 0 && blockIdx.x == 0) {
        int hits = 0;
        for (int i = 0; i < 2048; ++i) {
            unsigned e = (x[i] >> 7) & 0xFFu;
            hits += (e >= 0x8Du) ? 1 : 0;
        }
        *mode = (hits >= 16) ? 1 : 0;
    }
}

// ---- convert x (elements [off, off+n8*8)) to bf16 ----
__global__ void convert_x(const void* __restrict__ xin, bf16_t* __restrict__ xb,
                          const int* __restrict__ modep, long long off, long long n8)
{
    const long long i = (long long)blockIdx.x * blockDim.x + threadIdx.x;
    if (i >= n8) return;
    bf16x8 o;
    if (*modep) {
        const float* s = (const float*)xin + off + i * 8;
#pragma unroll
        for (int j = 0; j < 8; ++j) o[j] = f2bf(s[j]);
    } else {
        o = *(const bf16x8*)((const bf16_t*)xin + off + i * 8);
    }
    *(bf16x8*)(xb + i * 8) = o;
}

// ---- transpose the three weight matrices -> bf16 Wt[n][k] = W[k][n] ----
__global__ void transpose3(const void* __restrict__ Wq, const void* __restrict__ Wk,
                           const void* __restrict__ Wv, bf16_t* __restrict__ Wt,
                           const int* __restrict__ modep)
{
    const int md = *modep;
    const void* src = (blockIdx.z == 0) ? Wq : (blockIdx.z == 1) ? Wk : Wv;
    bf16_t* dst = Wt + (size_t)blockIdx.z * DM * DM;
    __shared__ bf16_t T[64][72];
    const int tid = threadIdx.x;
    const int r  = tid >> 2;   // 0..63
    const int cp = tid & 3;    // 16 elems each
    const int r0 = blockIdx.y * 64;  // k block
    const int c0 = blockIdx.x * 64;  // n block
    const size_t base = (size_t)(r0 + r) * DM + c0 + cp * 16;
    bf16_t tmp[16];
    if (md) {
        const float* s = (const float*)src + base;
#pragma unroll
        for (int j = 0; j < 16; ++j) tmp[j] = f2bf(s[j]);
    } else {
        const bf16_t* s = (const bf16_t*)src + base;
        bf16x8 a = *(const bf16x8*)s;
        bf16x8 b = *(const bf16x8*)(s + 8);
#pragma unroll
        for (int j = 0; j < 8; ++j) { tmp[j] = a[j]; tmp[8 + j] = b[j]; }
    }
#pragma unroll
    for (int j = 0; j < 16; ++j) T[cp * 16 + j][r] = tmp[j];
    __syncthreads();
    bf16_t* d = dst + (size_t)(c0 + r) * DM + r0 + cp * 16;
    bf16x8 w0, w1;
#pragma unroll
    for (int j = 0; j < 8; ++j) w0[j] = T[r][cp * 16 + j];
#pragma unroll
    for (int j = 0; j < 8; ++j) w1[j] = T[r][cp * 16 + 8 + j];
    *(bf16x8*)d = w0;
    *(bf16x8*)(d + 8) = w1;
}

// ============================================================================
// 256x256 NT gemm, 4-phase schedule with deep prefetch (T2+T3+T4+T5).
// 512 threads = 8 waves; per K-tile (BK=64) 4 phases; phase p computes
// quadrant (row-half p&1, col-half p>>1), 16 MFMA 16x16x32. K-loop as R5
// (proven; at K=1024 this is ~90% of the best-known plain-HIP 848 TF, m248).
// R6: EPI_SMAXT epilogue — fuses scale + 64-chunk softmax + transpose into
// the QK^T gemm, eliminating the separate softmax_t_inplace pass (128MB
// HBM round-trip + a dispatch). Alignment gift: each wave's 64-col span
// (cbase = bx*256 + nh*128 + cb*64) is exactly one softmax chunk; row
// reduce = 4 in-reg values + shfl_xor{1,2,4,8} within the 16-lane kg group
// (same rows, different cols). Transposed store: for fixed (nt,lm) a lane's
// 4 r-values are 4 consecutive d -> one 8B bf16x4 store to yt[e][d0..3].
// Softmax on fp32 accumulators (better than the old bf16 round-trip).
// ============================================================================
template <int MODE, bool DUALOUT>
__global__ __launch_bounds__(512, 2)
void gemm_nt8(const bf16_t* __restrict__ A, long long sA,
              const bf16_t* __restrict__ B, long long sB,
              void* __restrict__ C, long long sC, long long cOff,
              const void* __restrict__ bias, const int* __restrict__ modep,
              float scale)
{
    constexpr int K = 1024;
    constexpr int NT = K / 64;          // 16 K-tiles
    extern __shared__ bf16_t L[];       // 2*4*8192 bf16 = 128 KiB

    // ---- XCD-aware bijective swizzle (grid is 4 x 4 x z, nwg % 8 == 0) ----
    int bx, by, z;
    {
        const int nwg  = 16 * (int)gridDim.z;
        const int orig = (int)blockIdx.x + 4 * ((int)blockIdx.y + 4 * (int)blockIdx.z);
        const int nid  = (orig & 7) * (nwg >> 3) + (orig >> 3);
        bx = nid & 3; by = (nid >> 2) & 3; z = nid >> 4;
    }

    const bf16_t* Ab = A + (size_t)z * (size_t)sA;
    const bf16_t* Bb = B + (size_t)z * (size_t)sB;
    const int gm0 = by * 256, gn0 = bx * 256;

    const int tid  = threadIdx.x;
    const int lane = tid & 63;
    const int w    = tid >> 6;      // 0..7
    const int rb   = w >> 1;        // 0..3: 32-row band within each row-half
    const int cb   = w & 1;         // 0..1: 64-col band within each col-half
    const int lm   = lane & 15;
    const int kg   = lane >> 4;     // 0..3

    f32x4 acc[4][2][4];
#pragma unroll
    for (int p = 0; p < 4; ++p)
#pragma unroll
        for (int i = 0; i < 2; ++i)
#pragma unroll
            for (int j = 0; j < 4; ++j) acc[p][i][j] = (f32x4)0.0f;

    // fragment register sets
    bf16x8 af0[2][2], af1[2][2], bg0[4][2], bg1[4][2];

    // stage slot s of K-tile kt into buffer b (2 x global_load_lds / thread)
    // slots: 0=A-h0, 1=B-h0, 2=A-h1, 3=B-h1
    auto stage = [&](int kt, int s, int b) {
        const bf16_t* P  = (s & 1) ? Bb : Ab;
        const int     g0 = (s & 1) ? gn0 : gm0;
        const int     h  = (s >= 2) ? 1 : 0;
        bf16_t* dst = L + (b * 4 + s) * 8192;
#pragma unroll
        for (int i = 0; i < 2; ++i) {
            const int ci  = i * 512 + tid;
            const int row = ci >> 3;
            const int kc  = (ci & 7) ^ (row & 7);   // pre-swizzled source
            async_lds16(P + (size_t)(g0 + h * 128 + row) * K + kt * 64 + kc * 8,
                        dst + ci * 8);
        }
    };

    // fragment read: row r (0..127) within a half-slot, 8-elem chunk kc (0..7)
    auto rdfrag = [&](int b, int s, int r, int kc) -> bf16x8 {
        const int byte = r * 128 + ((kc ^ (r & 7)) * 16);
        return *(const bf16x8*)((const char*)(L + (b * 4 + s) * 8192) + byte);
    };
    auto rdA = [&](int b, int s, bf16x8 (&dst)[2][2]) {
#pragma unroll
        for (int mt = 0; mt < 2; ++mt)
#pragma unroll
            for (int kk = 0; kk < 2; ++kk)
                dst[mt][kk] = rdfrag(b, s, rb * 32 + mt * 16 + lm, kk * 4 + kg);
    };
    auto rdB = [&](int b, int s, bf16x8 (&dst)[4][2]) {
#pragma unroll
        for (int nt = 0; nt < 4; ++nt)
#pragma unroll
            for (int kk = 0; kk < 2; ++kk)
                dst[nt][kk] = rdfrag(b, s, cb * 64 + nt * 16 + lm, kk * 4 + kg);
    };

#define MFMA_PHASE(P, AF, BG)                                                  \
    __builtin_amdgcn_s_setprio(1);                                             \
    _Pragma("unroll")                                                          \
    for (int kk = 0; kk < 2; ++kk)                                             \
        _Pragma("unroll")                                                      \
        for (int mt = 0; mt < 2; ++mt)                                         \
            _Pragma("unroll")                                                  \
            for (int nt = 0; nt < 4; ++nt)                                     \
                acc[P][mt][nt] = __builtin_amdgcn_mfma_f32_16x16x32_bf16(      \
                    AF[mt][kk], BG[nt][kk], acc[P][mt][nt], 0, 0, 0);          \
    __builtin_amdgcn_s_setprio(0);

    // ---- prologue: stage tile0's 4 slots; publish s0,s1 (vmcnt(4)) ----
#pragma unroll
    for (int s = 0; s < 4; ++s) stage(0, s, 0);
    asm volatile("s_waitcnt vmcnt(4)" ::: "memory");
    __builtin_amdgcn_s_barrier();

#pragma unroll 1
    for (int kt = 0; kt < NT; ++kt) {
        const int cur = kt & 1;
        const int nxt = cur ^ 1;
        const int nkt = (kt + 1 < NT) ? kt + 1 : 0;    // dummy re-stage on last

        // ---- p0: read af0<-s0, bg0<-s1 | stage s0',s1' | MFMA q0 ----
        rdA(cur, 0, af0);
        rdB(cur, 1, bg0);
        stage(nkt, 0, nxt);
        stage(nkt, 1, nxt);
        __builtin_amdgcn_sched_barrier(0);
        MFMA_PHASE(0, af0, bg0)
        __builtin_amdgcn_sched_barrier(0);
        asm volatile("s_waitcnt vmcnt(6)" ::: "memory");   // publish s2
        __builtin_amdgcn_s_barrier();

        // ---- p1: read af1<-s2 | stage s2',s3' | MFMA q1 ----
        rdA(cur, 2, af1);
        stage(nkt, 2, nxt);
        stage(nkt, 3, nxt);
        __builtin_amdgcn_sched_barrier(0);
        MFMA_PHASE(1, af1, bg0)
        __builtin_amdgcn_sched_barrier(0);
        asm volatile("s_waitcnt vmcnt(8)" ::: "memory");   // publish s3
        __builtin_amdgcn_s_barrier();

        // ---- p2+p3 fused: read bg1<-s3 | MFMA q2, q3 (32-MFMA cluster) ----
        rdB(cur, 3, bg1);
        __builtin_amdgcn_sched_barrier(0);
        MFMA_PHASE(2, af0, bg1)
        MFMA_PHASE(3, af1, bg1)
        __builtin_amdgcn_sched_barrier(0);
        asm volatile("s_waitcnt vmcnt(4)" ::: "memory");   // publish s0',s1'
        __builtin_amdgcn_s_barrier();
    }
#undef MFMA_PHASE

    if constexpr (MODE == EPI_SMAXT) {
        // ---- fused scale + 64-chunk softmax + transposed store ----
        // acc rows d = rbase+mt*16+kg*4+r; cols e = cbase+nt*16+lm.
        // Each (wave,p,mt,kg-group) holds 4 full softmax rows of one
        // 64-col chunk: reduce over nt (in-reg) then lm (shfl_xor 1,2,4,8).
        bf16_t* Y = (bf16_t*)C + (size_t)cOff + (size_t)z * sC;
#pragma unroll
        for (int p = 0; p < 4; ++p) {
            const int rbase = gm0 + (p & 1) * 128 + rb * 32;
            const int cbase = gn0 + (p >> 1) * 128 + cb * 64;
#pragma unroll
            for (int mt = 0; mt < 2; ++mt) {
                float ex[4][4];
                float mx[4], sm[4];
#pragma unroll
                for (int r = 0; r < 4; ++r) mx[r] = -3.0e38f;
#pragma unroll
                for (int nt = 0; nt < 4; ++nt)
#pragma unroll
                    for (int r = 0; r < 4; ++r) {
                        ex[nt][r] = acc[p][mt][nt][r] * scale;
                        mx[r] = fmaxf(mx[r], ex[nt][r]);
                    }
#pragma unroll
                for (int st = 1; st <= 8; st <<= 1)
#pragma unroll
                    for (int r = 0; r < 4; ++r)
                        mx[r] = fmaxf(mx[r], __shfl_xor(mx[r], st));
#pragma unroll
                for (int r = 0; r < 4; ++r) sm[r] = 0.f;
#pragma unroll
                for (int nt = 0; nt < 4; ++nt)
#pragma unroll
                    for (int r = 0; r < 4; ++r) {
                        ex[nt][r] = __expf(ex[nt][r] - mx[r]);
                        sm[r] += ex[nt][r];
                    }
#pragma unroll
                for (int st = 1; st <= 8; st <<= 1)
#pragma unroll
                    for (int r = 0; r < 4; ++r)
                        sm[r] += __shfl_xor(sm[r], st);
#pragma unroll
                for (int r = 0; r < 4; ++r) sm[r] = 1.0f / sm[r];
                const int d0 = rbase + mt * 16 + kg * 4;
#pragma unroll
                for (int nt = 0; nt < 4; ++nt) {
                    bf16x4 o;
#pragma unroll
                    for (int r = 0; r < 4; ++r) o[r] = f2bf(ex[nt][r] * sm[r]);
                    const int e = cbase + nt * 16 + lm;
                    *(bf16x4*)(Y + (size_t)e * 1024 + d0) = o;
                }
            }
        }
        return;
    } else {
        // ---- generic epilogue: C/D layout col=lane&15, row=kg*4+r ----
        const int md = *modep;
#pragma unroll
        for (int p = 0; p < 4; ++p) {
            const int rbase = gm0 + (p & 1) * 128 + rb * 32;
            const int cbase = gn0 + (p >> 1) * 128 + cb * 64;
#pragma unroll
            for (int mt = 0; mt < 2; ++mt) {
                float rbias[4];
                if (MODE == EPI_BIAS_ROW) {
#pragma unroll
                    for (int r = 0; r < 4; ++r) {
                        const int i = rbase + mt * 16 + kg * 4 + r;
                        rbias[r] = md ? ((const float*)bias)[i] : bf2f(((const bf16_t*)bias)[i]);
                    }
                }
#pragma unroll
                for (int nt = 0; nt < 4; ++nt) {
                    const int col = cbase + nt * 16 + lm;
                    float cbias = 0.f;
                    if (MODE == EPI_BIAS_COL)
                        cbias = md ? ((const float*)bias)[col] : bf2f(((const bf16_t*)bias)[col]);
#pragma unroll
                    for (int r = 0; r < 4; ++r) {
                        const int row = rbase + mt * 16 + kg * 4 + r;
                        float vv = acc[p][mt][nt][r];
                        if (MODE == EPI_BIAS_ROW) vv += rbias[r];
                        if (MODE == EPI_BIAS_COL) vv += cbias;
                        if (MODE == EPI_SCALE)    vv *= scale;
                        const size_t off = (size_t)cOff + (size_t)z * sC + (size_t)row * 1024 + col;
                        if (DUALOUT && md) ((float*)C)[off] = vv;
                        else               ((bf16_t*)C)[off] = f2bf(vv);
                    }
                }
            }
        }
    }
}

extern "C" void kernel_launch(void* const* d_in, const int* in_sizes, int n_in,
                              void* d_out, int out_size, void* d_ws, size_t ws_size,
                              hipStream_t stream)
{
    const void* x  = d_in[0];
    const void* Wq = d_in[1];
    const void* bq = d_in[2];
    const void* Wk = d_in[3];
    const void* bk = d_in[4];
    const void* Wv = d_in[5];
    const void* bv = d_in[6];

    // one-time: allow 128 KiB dynamic LDS on the gemm instantiations
    static bool attr_done = false;
    if (!attr_done) {
        hipFuncSetAttribute((const void*)gemm_nt8<EPI_BIAS_ROW, false>,
                            hipFuncAttributeMaxDynamicSharedMemorySize, 131072);
        hipFuncSetAttribute((const void*)gemm_nt8<EPI_BIAS_COL, false>,
                            hipFuncAttributeMaxDynamicSharedMemorySize, 131072);
        hipFuncSetAttribute((const void*)gemm_nt8<EPI_SMAXT, false>,
                            hipFuncAttributeMaxDynamicSharedMemorySize, 131072);
        hipFuncSetAttribute((const void*)gemm_nt8<EPI_NONE, true>,
                            hipFuncAttributeMaxDynamicSharedMemorySize, 131072);
        attr_done = true;
    }

    // ws layout: [mode int | pad to 256] [Wt 6MB] [xb CB] [qt CB] [kt CB] [y CB]
    char* ws = (char*)d_ws;
    int* mode = (int*)ws;
    const size_t MB2 = (size_t)DM * DM * 2;
    const size_t hdr = 256;
    int CB = NB;
    while (CB > 1 && hdr + 3 * MB2 + 4 * (size_t)CB * MB2 > ws_size) CB >>= 1;

    bf16_t* Wt = (bf16_t*)(ws + hdr);
    bf16_t* xb = (bf16_t*)(ws + hdr + 3 * MB2);
    bf16_t* qt = xb + (size_t)CB * DM * DM;
    bf16_t* kt = qt + (size_t)CB * DM * DM;
    bf16_t* y  = kt + (size_t)CB * DM * DM;
    bf16_t* v  = qt;   // qt dead after QK^T; reuse for V

    detect_mode<<<1, 64, 0, stream>>>((const unsigned short*)x, mode);
    transpose3<<<dim3(16, 16, 3), 256, 0, stream>>>(Wq, Wk, Wv, Wt, mode);

    const long long msz = (long long)DM * DM;
    for (int c = 0; c < NB; c += CB) {
        const int zb = (NB - c < CB) ? (NB - c) : CB;
        const long long n8 = (long long)zb * msz / 8;
        convert_x<<<(int)((n8 + 255) / 256), 256, 0, stream>>>(x, xb, mode, (long long)c * msz, n8);

        const dim3 g8(4, 4, zb), blk8(512);
        // qt[b][d][s] = Wq^T x^T + bq (row bias)
        gemm_nt8<EPI_BIAS_ROW, false><<<g8, blk8, 131072, stream>>>(Wt, 0, xb, msz, qt, msz, 0, bq, mode, 1.f);
        // kt[b][e][s]
        gemm_nt8<EPI_BIAS_ROW, false><<<g8, blk8, 131072, stream>>>(Wt + msz, 0, xb, msz, kt, msz, 0, bk, mode, 1.f);
        // yt[b][e][d] = softmax_64chunk(qt.kt/8) transposed — fused epilogue
        gemm_nt8<EPI_SMAXT, false><<<g8, blk8, 131072, stream>>>(qt, msz, kt, msz, y, msz, 0, nullptr, mode, 0.125f);
        // v[b][s][d] = x Wv^T + bv (col bias) -> qt slab
        gemm_nt8<EPI_BIAS_COL, false><<<g8, blk8, 131072, stream>>>(xb, msz, Wt + 2 * msz, 0, v, msz, 0, bv, mode, 1.f);
        // out[b][s][e] = v . yt   (dual-dtype output)
        gemm_nt8<EPI_NONE, true><<<g8, blk8, 131072, stream>>>(v, msz, y, msz, d_out, msz, (long long)c * msz, nullptr, mode, 1.f);
    }
}